// Round 1
// baseline (130.105 us; speedup 1.0000x reference)
//
#include <hip/hip_runtime.h>

// MultiHeadAttention_137438953529 on gfx950.
// B=8, S=1024, E=1024, H=16, D=64.  Key insight: the reference's reshapes are
// flat reinterpretations, so attention mixes only groups of 8 consecutive rows
// of the (8192 x 1024) projected matrices, per 64-wide head slice.

typedef __attribute__((ext_vector_type(4))) float f32x4;
typedef __attribute__((ext_vector_type(8))) short bf16x8;   // MFMA A/B fragment (8 bf16)
typedef __attribute__((ext_vector_type(8))) unsigned short u16x8;

__device__ __forceinline__ unsigned short f2bf(float f) {
  unsigned int u = __builtin_bit_cast(unsigned int, f);
  u += 0x7fffu + ((u >> 16) & 1u);          // round-to-nearest-even
  return (unsigned short)(u >> 16);
}
__device__ __forceinline__ float bf2f(unsigned short b) {
  return __builtin_bit_cast(float, ((unsigned int)b) << 16);
}

__device__ __forceinline__ void gload_lds16(const unsigned short* g, unsigned short* l) {
  __builtin_amdgcn_global_load_lds(
      (const __attribute__((address_space(1))) unsigned int*)g,
      (__attribute__((address_space(3))) unsigned int*)l, 16, 0, 0);
}

// ---------------------------------------------------------------- convert W
__global__ __launch_bounds__(256) void cvt_bf16_kernel(const float* __restrict__ src,
                                                       unsigned short* __restrict__ dst,
                                                       int n8) {
  int i = blockIdx.x * blockDim.x + threadIdx.x;
  if (i >= n8) return;
  const f32x4* s = reinterpret_cast<const f32x4*>(src) + (size_t)i * 2;
  f32x4 a = s[0], b = s[1];
  u16x8 o;
  o[0] = f2bf(a[0]); o[1] = f2bf(a[1]); o[2] = f2bf(a[2]); o[3] = f2bf(a[3]);
  o[4] = f2bf(b[0]); o[5] = f2bf(b[1]); o[6] = f2bf(b[2]); o[7] = f2bf(b[3]);
  reinterpret_cast<u16x8*>(dst)[i] = o;
}

// ------------------------------------------------------- fused QKV projection
// C[8192x1024] = X @ W^T + bias, per proj (blockIdx.z).  128x128 tile, BK=32,
// 4 waves each owning 64x64 (4x4 frags of 16x16x32 bf16 MFMA).
// A (X, f32) is reg-staged with f32->bf16 convert + 1-step prefetch;
// B (W, bf16 pre-converted) is staged via global_load_lds width=16.
__global__ __launch_bounds__(256) void gemm_qkv(
    const float* __restrict__ Xq, const float* __restrict__ Xk, const float* __restrict__ Xv,
    const unsigned short* __restrict__ Wb,
    const float* __restrict__ bq, const float* __restrict__ bk, const float* __restrict__ bv,
    unsigned short* __restrict__ QKV) {
  const int proj = blockIdx.z;
  const float* X = (proj == 0) ? Xq : (proj == 1) ? Xk : Xv;
  const float* bias = (proj == 0) ? bq : (proj == 1) ? bk : bv;
  const unsigned short* W = Wb + (size_t)proj * (1024u * 1024u);
  unsigned short* O = QKV + (size_t)proj * (8192u * 1024u);

  const int rowBase = blockIdx.x * 128;
  const int colBase = blockIdx.y * 128;

  __shared__ alignas(16) unsigned short As[128 * 32];  // [m][k] bf16
  __shared__ alignas(16) unsigned short Bs[128 * 32];  // [n][k] bf16

  const int t = threadIdx.x;
  const int l = t & 63;
  const int w = t >> 6;
  const int wr = w >> 1, wc = w & 1;

  f32x4 acc[4][4];
#pragma unroll
  for (int m = 0; m < 4; ++m)
#pragma unroll
    for (int n = 0; n < 4; ++n) acc[m][n] = f32x4{0.f, 0.f, 0.f, 0.f};

  // staging map: chunk c covers rows c*64 + t/4, k-slice (t%4)*8 .. +8
  const int am = t >> 2;
  const int ak = (t & 3) << 3;
  const float* a0 = X + (size_t)(rowBase + am) * 1024 + ak;
  const float* a1 = X + (size_t)(rowBase + 64 + am) * 1024 + ak;
  const unsigned short* b0 = W + (size_t)(colBase + am) * 1024 + ak;
  const unsigned short* b1 = W + (size_t)(colBase + 64 + am) * 1024 + ak;

  // fragment read positions
  const int arow = wr * 64 + (l & 15);
  const int brow = wc * 64 + (l & 15);
  const int koff = (l >> 4) * 8;

  f32x4 cur[4], nxt[4];
  cur[0] = *reinterpret_cast<const f32x4*>(a0);
  cur[1] = *reinterpret_cast<const f32x4*>(a0 + 4);
  cur[2] = *reinterpret_cast<const f32x4*>(a1);
  cur[3] = *reinterpret_cast<const f32x4*>(a1 + 4);

  for (int k0 = 0; k0 < 1024; k0 += 32) {
    __syncthreads();  // all waves done reading previous LDS tiles
    // B: async global->LDS (linear dest = wave base + lane*16)
    gload_lds16(b0 + k0, Bs + t * 8);
    gload_lds16(b1 + k0, Bs + 2048 + t * 8);
    // prefetch next A slice (latency hidden under this iter's MFMA phase)
    if (k0 + 32 < 1024) {
      nxt[0] = *reinterpret_cast<const f32x4*>(a0 + k0 + 32);
      nxt[1] = *reinterpret_cast<const f32x4*>(a0 + k0 + 36);
      nxt[2] = *reinterpret_cast<const f32x4*>(a1 + k0 + 32);
      nxt[3] = *reinterpret_cast<const f32x4*>(a1 + k0 + 36);
    }
    // A: convert current f32 slice to bf16, write to LDS
    u16x8 pa, pb;
    pa[0] = f2bf(cur[0][0]); pa[1] = f2bf(cur[0][1]); pa[2] = f2bf(cur[0][2]); pa[3] = f2bf(cur[0][3]);
    pa[4] = f2bf(cur[1][0]); pa[5] = f2bf(cur[1][1]); pa[6] = f2bf(cur[1][2]); pa[7] = f2bf(cur[1][3]);
    pb[0] = f2bf(cur[2][0]); pb[1] = f2bf(cur[2][1]); pb[2] = f2bf(cur[2][2]); pb[3] = f2bf(cur[2][3]);
    pb[4] = f2bf(cur[3][0]); pb[5] = f2bf(cur[3][1]); pb[6] = f2bf(cur[3][2]); pb[7] = f2bf(cur[3][3]);
    *reinterpret_cast<u16x8*>(As + t * 8) = pa;
    *reinterpret_cast<u16x8*>(As + 2048 + t * 8) = pb;
    __syncthreads();  // drains vmcnt (global_load_lds) + lgkm (ds_write)

    bf16x8 af[4], bfr[4];
#pragma unroll
    for (int m = 0; m < 4; ++m)
      af[m] = *reinterpret_cast<const bf16x8*>(As + (arow + m * 16) * 32 + koff);
#pragma unroll
    for (int n = 0; n < 4; ++n)
      bfr[n] = *reinterpret_cast<const bf16x8*>(Bs + (brow + n * 16) * 32 + koff);
#pragma unroll
    for (int m = 0; m < 4; ++m)
#pragma unroll
      for (int n = 0; n < 4; ++n)
        acc[m][n] = __builtin_amdgcn_mfma_f32_16x16x32_bf16(af[m], bfr[n], acc[m][n], 0, 0, 0);

    cur[0] = nxt[0]; cur[1] = nxt[1]; cur[2] = nxt[2]; cur[3] = nxt[3];
  }

  // epilogue: C/D layout col=lane&15, row=(lane>>4)*4+reg
#pragma unroll
  for (int n = 0; n < 4; ++n) {
    const int col = colBase + wc * 64 + n * 16 + (l & 15);
    const float bn = bias[col];
#pragma unroll
    for (int m = 0; m < 4; ++m) {
      const int row0 = rowBase + wr * 64 + m * 16 + (l >> 4) * 4;
#pragma unroll
      for (int j = 0; j < 4; ++j)
        O[(size_t)(row0 + j) * 1024 + col] = f2bf(acc[m][n][j] + bn);
    }
  }
}

// ------------------------------------------------------------------ attention
// thread = (n group, head h, d-quarter dq, row-half rh): computes 4 q-rows x
// 16 d-cols of the 8-key attention.  Partial QK dots reduced across the 4
// dq lanes via shfl_xor.  Wave reads are 2KB-contiguous per K/V row.
__global__ __launch_bounds__(256) void attn_kernel(const unsigned short* __restrict__ QKV,
                                                   float* __restrict__ out) {
  const int t = threadIdx.x;
  const int lane = t & 63;
  const int dq = lane & 3;
  const int h = (lane >> 2) & 15;
  const int rh = (t >> 6) & 1;
  const int n = blockIdx.x * 2 + (t >> 7);

  const unsigned short* Q = QKV;
  const unsigned short* K = QKV + (size_t)8388608;
  const unsigned short* V = QKV + (size_t)16777216;
  const size_t gbase = (size_t)n * 8192;   // row n*8 of the 8192-row space
  const int coff = h * 64 + dq * 16;

  float q[4][16];
#pragma unroll
  for (int r = 0; r < 4; ++r) {
    const unsigned short* qp = Q + gbase + (size_t)(rh * 4 + r) * 1024 + coff;
    u16x8 a = *reinterpret_cast<const u16x8*>(qp);
    u16x8 b = *reinterpret_cast<const u16x8*>(qp + 8);
#pragma unroll
    for (int c = 0; c < 8; ++c) { q[r][c] = bf2f(a[c]); q[r][8 + c] = bf2f(b[c]); }
  }

  float s[4][8];
#pragma unroll
  for (int r = 0; r < 4; ++r)
#pragma unroll
    for (int j = 0; j < 8; ++j) s[r][j] = 0.f;

#pragma unroll
  for (int j = 0; j < 8; ++j) {
    const unsigned short* kp = K + gbase + (size_t)j * 1024 + coff;
    u16x8 a = *reinterpret_cast<const u16x8*>(kp);
    u16x8 b = *reinterpret_cast<const u16x8*>(kp + 8);
    float kv[16];
#pragma unroll
    for (int c = 0; c < 8; ++c) { kv[c] = bf2f(a[c]); kv[8 + c] = bf2f(b[c]); }
#pragma unroll
    for (int r = 0; r < 4; ++r) {
      float acc = 0.f;
#pragma unroll
      for (int c = 0; c < 16; ++c) acc += q[r][c] * kv[c];
      s[r][j] += acc;
    }
  }

  // full 64-d dot = sum over the 4 dq lanes
#pragma unroll
  for (int r = 0; r < 4; ++r)
#pragma unroll
    for (int j = 0; j < 8; ++j) {
      float v = s[r][j];
      v += __shfl_xor(v, 1, 64);
      v += __shfl_xor(v, 2, 64);
      s[r][j] = v;
    }

  float p[4][8];
#pragma unroll
  for (int r = 0; r < 4; ++r) {
    float mx = s[r][0];
#pragma unroll
    for (int j = 1; j < 8; ++j) mx = fmaxf(mx, s[r][j]);
    float sum = 0.f;
#pragma unroll
    for (int j = 0; j < 8; ++j) {
      float e = __expf(0.125f * (s[r][j] - mx));  // SCALE = 1/sqrt(64)
      p[r][j] = e;
      sum += e;
    }
    float inv = 1.f / sum;
#pragma unroll
    for (int j = 0; j < 8; ++j) p[r][j] *= inv;
  }

  float o[4][16];
#pragma unroll
  for (int r = 0; r < 4; ++r)
#pragma unroll
    for (int c = 0; c < 16; ++c) o[r][c] = 0.f;

#pragma unroll
  for (int j = 0; j < 8; ++j) {
    const unsigned short* vp = V + gbase + (size_t)j * 1024 + coff;
    u16x8 a = *reinterpret_cast<const u16x8*>(vp);
    u16x8 b = *reinterpret_cast<const u16x8*>(vp + 8);
    float vv[16];
#pragma unroll
    for (int c = 0; c < 8; ++c) { vv[c] = bf2f(a[c]); vv[8 + c] = bf2f(b[c]); }
#pragma unroll
    for (int r = 0; r < 4; ++r)
#pragma unroll
      for (int c = 0; c < 16; ++c) o[r][c] += p[r][j] * vv[c];
  }

#pragma unroll
  for (int r = 0; r < 4; ++r) {
    float* op = out + gbase + (size_t)(rh * 4 + r) * 1024 + coff;
    f32x4 v0 = {o[r][0], o[r][1], o[r][2], o[r][3]};
    f32x4 v1 = {o[r][4], o[r][5], o[r][6], o[r][7]};
    f32x4 v2 = {o[r][8], o[r][9], o[r][10], o[r][11]};
    f32x4 v3 = {o[r][12], o[r][13], o[r][14], o[r][15]};
    reinterpret_cast<f32x4*>(op)[0] = v0;
    reinterpret_cast<f32x4*>(op)[1] = v1;
    reinterpret_cast<f32x4*>(op)[2] = v2;
    reinterpret_cast<f32x4*>(op)[3] = v3;
  }
}

// ------------------------------------------------------------------- launch
extern "C" void kernel_launch(void* const* d_in, const int* in_sizes, int n_in,
                              void* d_out, int out_size, void* d_ws, size_t ws_size,
                              hipStream_t stream) {
  const float* Xq = (const float*)d_in[0];
  const float* Xk = (const float*)d_in[1];
  const float* Xv = (const float*)d_in[2];
  const float* Wq = (const float*)d_in[3];
  const float* bq = (const float*)d_in[4];
  const float* Wk = (const float*)d_in[5];
  const float* bk = (const float*)d_in[6];
  const float* Wv = (const float*)d_in[7];
  const float* bv = (const float*)d_in[8];

  unsigned short* ws = (unsigned short*)d_ws;
  unsigned short* Wb = ws;                                  // 3 x 1M bf16 (6 MB)
  unsigned short* QKV = ws + (size_t)3 * 1024 * 1024;       // 3 x 8M bf16 (50 MB)

  // W -> bf16  (each 1048576 f32 -> 131072 x 8)
  cvt_bf16_kernel<<<512, 256, 0, stream>>>(Wq, Wb, 131072);
  cvt_bf16_kernel<<<512, 256, 0, stream>>>(Wk, Wb + 1048576, 131072);
  cvt_bf16_kernel<<<512, 256, 0, stream>>>(Wv, Wb + 2097152, 131072);

  // fused Q/K/V projections
  gemm_qkv<<<dim3(64, 8, 3), 256, 0, stream>>>(Xq, Xk, Xv, Wb, bq, bk, bv, QKV);

  // grouped 8-key attention
  attn_kernel<<<512, 256, 0, stream>>>(QKV, (float*)d_out);
}

// Round 2
// 123.305 us; speedup vs baseline: 1.0551x; 1.0551x over previous
//
#include <hip/hip_runtime.h>

// MultiHeadAttention_137438953529 on gfx950.
// B=8, S=1024, E=1024, H=16, D=64.  The reference's reshapes are flat
// reinterpretations => attention mixes only groups of 8 consecutive rows of
// the (8192 x 1024) projected matrices, per 64-wide head slice.
//
// R2: GEMM rebuilt as 3-buffer deep-pipelined kernel (BM=128,BN=256,BK=64,
// 8 waves), counted vmcnt(8) per K-tile (never a mid-loop drain), XOR-swizzled
// LDS (pre-swizzled W in ws for linear global_load_lds; reg-staged A with
// swizzled ds_write), s_setprio around MFMA clusters.

typedef __attribute__((ext_vector_type(4))) float f32x4;
typedef __attribute__((ext_vector_type(8))) short bf16x8;   // MFMA A/B fragment
typedef __attribute__((ext_vector_type(8))) unsigned short u16x8;

#define WAIT_LGKM0 asm volatile("s_waitcnt lgkmcnt(0)" ::: "memory")
#define WAIT_VM(n) asm volatile("s_waitcnt vmcnt(" #n ")" ::: "memory")

__device__ __forceinline__ unsigned short f2bf(float f) {
  unsigned int u = __builtin_bit_cast(unsigned int, f);
  u += 0x7fffu + ((u >> 16) & 1u);          // round-to-nearest-even
  return (unsigned short)(u >> 16);
}
__device__ __forceinline__ float bf2f(unsigned short b) {
  return __builtin_bit_cast(float, ((unsigned int)b) << 16);
}
__device__ __forceinline__ u16x8 pack8(f32x4 a, f32x4 b) {
  u16x8 o;
  o[0] = f2bf(a[0]); o[1] = f2bf(a[1]); o[2] = f2bf(a[2]); o[3] = f2bf(a[3]);
  o[4] = f2bf(b[0]); o[5] = f2bf(b[1]); o[6] = f2bf(b[2]); o[7] = f2bf(b[3]);
  return o;
}

__device__ __forceinline__ void gload_lds16(const unsigned short* g, unsigned short* l) {
  __builtin_amdgcn_global_load_lds(
      (const __attribute__((address_space(1))) unsigned int*)g,
      (__attribute__((address_space(3))) unsigned int*)l, 16, 0, 0);
}

// ------------------------------------------------- W -> bf16, PRE-SWIZZLED
// Stores chunk kc (8 bf16) of row r at chunk position (kc&0x78)|((kc^r)&7),
// so the GEMM's linear global_load_lds staging lands the tile already in the
// bank-conflict-free XOR layout (slot = chunk ^ (row&7) within each 8-chunk
// BK=64 window; windows are 8-chunk aligned so the high bits pass through).
__global__ __launch_bounds__(256) void cvt_w_swz(const float* __restrict__ Wq,
                                                 const float* __restrict__ Wk,
                                                 const float* __restrict__ Wv,
                                                 unsigned short* __restrict__ Wb) {
  int i = blockIdx.x * 256 + threadIdx.x;     // 0 .. 393216 (3 * 131072 chunks)
  int proj = i >> 17;
  int local = i & 131071;
  const float* src = (proj == 0 ? Wq : proj == 1 ? Wk : Wv) + (size_t)local * 8;
  int row = local >> 7;                       // 0..1023
  int kc = local & 127;                       // chunk of 8 elems within row
  int dkc = (kc & 0x78) | ((kc ^ row) & 7);
  f32x4 a = reinterpret_cast<const f32x4*>(src)[0];
  f32x4 b = reinterpret_cast<const f32x4*>(src)[1];
  *reinterpret_cast<u16x8*>(Wb + (size_t)proj * 1048576 + (size_t)row * 1024 + dkc * 8) =
      pack8(a, b);
}

// ------------------------------------------------------------ QKV projection
// C[8192x1024] = X @ W^T + bias per proj.  BM=128 BN=256 BK=64, 512 threads,
// 8 waves (2x4), per-wave 64x64 (4x4 frags of 16x16x32 bf16 MFMA).
// LDS: 3 buffers x (A 8192 + B 16384 elems) = 73728 bf16 = 144 KiB.
// Pipeline: iter kt issues A-f32 loads + B global_load_lds for kt+2,
// ds_writes A(kt+1) (from regs loaded last iter), computes kt, then
// lgkmcnt(0) + vmcnt(8) + s_barrier.  vmcnt(8) == this iter's 8 VMEM issues,
// so everything issued in earlier iters (all of kt+1's tile) has landed.

__device__ __forceinline__ void issueA(const float* __restrict__ X, int rowBase,
                                       int kt2, int t, f32x4 r[4]) {
  const float* src = X + (size_t)(rowBase + (t >> 2)) * 1024 + kt2 * 64 + (t & 3) * 16;
#pragma unroll
  for (int i = 0; i < 4; ++i) r[i] = *reinterpret_cast<const f32x4*>(src + i * 4);
}

__device__ __forceinline__ void stageB(const unsigned short* __restrict__ W,
                                       unsigned short* ldsB, int colBase, int kt2, int t) {
#pragma unroll
  for (int j = 0; j < 4; ++j) {
    int o = ((t >> 6) * 4 + j) * 1024 + (t & 63) * 16;  // byte offset in 32 KiB tile
    int row = o >> 7, cb = o & 127;
    const unsigned short* src = W + (size_t)(colBase + row) * 1024 + kt2 * 64 + (cb >> 1);
    gload_lds16(src, ldsB + (o >> 1));
  }
}

__device__ __forceinline__ void writeA(unsigned short* ldsA, int t, const f32x4 r[4]) {
  int row = t >> 2;
  int c0 = (t & 3) * 2;
  int x = row & 7;
  *reinterpret_cast<u16x8*>(ldsA + row * 64 + ((c0 ^ x) * 8)) = pack8(r[0], r[1]);
  *reinterpret_cast<u16x8*>(ldsA + row * 64 + (((c0 + 1) ^ x) * 8)) = pack8(r[2], r[3]);
}

__device__ __forceinline__ void computeTile(const unsigned short* ldsBuf, int l, int wr,
                                            int wc, f32x4 acc[4][4]) {
  const unsigned short* A = ldsBuf;           // [128][64] swizzled
  const unsigned short* B = ldsBuf + 8192;    // [256][64] swizzled
  const int rA = wr * 64 + (l & 15);
  const int rB = wc * 64 + (l & 15);
  const int g = l >> 4, x7 = l & 7;
#pragma unroll
  for (int s = 0; s < 2; ++s) {
    const int slot = ((s * 4 + g) ^ x7) * 8;
    bf16x8 af[4], bf[4];
#pragma unroll
    for (int m = 0; m < 4; ++m)
      af[m] = *reinterpret_cast<const bf16x8*>(A + (rA + m * 16) * 64 + slot);
#pragma unroll
    for (int n = 0; n < 4; ++n)
      bf[n] = *reinterpret_cast<const bf16x8*>(B + (rB + n * 16) * 64 + slot);
    __builtin_amdgcn_s_setprio(1);
#pragma unroll
    for (int m = 0; m < 4; ++m)
#pragma unroll
      for (int n = 0; n < 4; ++n)
        acc[m][n] = __builtin_amdgcn_mfma_f32_16x16x32_bf16(af[m], bf[n], acc[m][n], 0, 0, 0);
    __builtin_amdgcn_s_setprio(0);
  }
}

__global__ __launch_bounds__(512, 2) void gemm_qkv2(
    const float* __restrict__ Xq, const float* __restrict__ Xk, const float* __restrict__ Xv,
    const unsigned short* __restrict__ Wb,
    const float* __restrict__ bq, const float* __restrict__ bk, const float* __restrict__ bv,
    unsigned short* __restrict__ QKV) {
  __shared__ unsigned short lds[73728];       // 3 x (8192 A + 16384 B) = 144 KiB

  const int proj = blockIdx.z;
  const float* X = (proj == 0) ? Xq : (proj == 1) ? Xk : Xv;
  const float* bias = (proj == 0) ? bq : (proj == 1) ? bk : bv;
  const unsigned short* W = Wb + (size_t)proj * 1048576;
  unsigned short* O = QKV + (size_t)proj * 8388608;

  const int rowBase = blockIdx.x * 128;
  const int colBase = blockIdx.y * 256;
  const int t = threadIdx.x;
  const int l = t & 63;
  const int w = t >> 6;
  const int wr = w >> 2, wc = w & 3;

  f32x4 acc[4][4];
#pragma unroll
  for (int m = 0; m < 4; ++m)
#pragma unroll
    for (int n = 0; n < 4; ++n) acc[m][n] = f32x4{0.f, 0.f, 0.f, 0.f};

  f32x4 aR0[4], aR1[4];

  // ---- prologue: stage K-tiles 0 and 1
  issueA(X, rowBase, 0, t, aR0);
  stageB(W, lds + 8192, colBase, 0, t);                 // buf0 B
  issueA(X, rowBase, 1, t, aR1);
  stageB(W, lds + 24576 + 8192, colBase, 1, t);         // buf1 B
  writeA(lds, t, aR0);                                  // buf0 A (waits aR0)
  WAIT_LGKM0;
  WAIT_VM(8);                                           // kt0 fully landed
  __builtin_amdgcn_sched_barrier(0);
  __builtin_amdgcn_s_barrier();
  __builtin_amdgcn_sched_barrier(0);

  int b0 = 0, b1 = 24576, b2 = 49152;  // compute buf, next buf, stage buf

#pragma unroll 2
  for (int kt = 0; kt < 16; ++kt) {
    // (a)+(b): issue kt+2's tile (A into regs, B direct-to-LDS)
    if (kt + 2 < 16) {
      if ((kt & 1) == 0) issueA(X, rowBase, kt + 2, t, aR0);
      else               issueA(X, rowBase, kt + 2, t, aR1);
      stageB(W, lds + b2 + 8192, colBase, kt + 2, t);
    }
    // (c): ds_write A(kt+1) from regs issued last iter (compiler inserts the
    // precise vmcnt for the register dependence)
    if (kt + 1 < 16) {
      if ((kt & 1) == 0) writeA(lds + b1, t, aR1);
      else               writeA(lds + b1, t, aR0);
    }
    // (d): compute kt
    computeTile(lds + b0, l, wr, wc, acc);
    // (e): transition
    if (kt < 15) {
      WAIT_LGKM0;
      if (kt < 14) { WAIT_VM(8); } else { WAIT_VM(0); }
      __builtin_amdgcn_sched_barrier(0);
      __builtin_amdgcn_s_barrier();
      __builtin_amdgcn_sched_barrier(0);
    }
    int tmp = b0; b0 = b1; b1 = b2; b2 = tmp;
  }

  // ---- epilogue: C/D layout col=lane&15, row=(lane>>4)*4+reg
#pragma unroll
  for (int n = 0; n < 4; ++n) {
    const int col = colBase + wc * 64 + n * 16 + (l & 15);
    const float bn = bias[col];
#pragma unroll
    for (int m = 0; m < 4; ++m) {
      const int row0 = rowBase + wr * 64 + m * 16 + (l >> 4) * 4;
#pragma unroll
      for (int j = 0; j < 4; ++j)
        O[(size_t)(row0 + j) * 1024 + col] = f2bf(acc[m][n][j] + bn);
    }
  }
}

// ------------------------------------------------------------------ attention
// thread = (n group, head h, d-quarter dq, row-half rh): 4 q-rows x 16 d-cols
// of the 8-key attention; QK partial dots reduced across 4 dq lanes.
__global__ __launch_bounds__(256) void attn_kernel(const unsigned short* __restrict__ QKV,
                                                   float* __restrict__ out) {
  const int t = threadIdx.x;
  const int lane = t & 63;
  const int dq = lane & 3;
  const int h = (lane >> 2) & 15;
  const int rh = (t >> 6) & 1;
  const int n = blockIdx.x * 2 + (t >> 7);

  const unsigned short* Q = QKV;
  const unsigned short* K = QKV + (size_t)8388608;
  const unsigned short* V = QKV + (size_t)16777216;
  const size_t gbase = (size_t)n * 8192;
  const int coff = h * 64 + dq * 16;

  float q[4][16];
#pragma unroll
  for (int r = 0; r < 4; ++r) {
    const unsigned short* qp = Q + gbase + (size_t)(rh * 4 + r) * 1024 + coff;
    u16x8 a = *reinterpret_cast<const u16x8*>(qp);
    u16x8 b = *reinterpret_cast<const u16x8*>(qp + 8);
#pragma unroll
    for (int c = 0; c < 8; ++c) { q[r][c] = bf2f(a[c]); q[r][8 + c] = bf2f(b[c]); }
  }

  float s[4][8];
#pragma unroll
  for (int r = 0; r < 4; ++r)
#pragma unroll
    for (int j = 0; j < 8; ++j) s[r][j] = 0.f;

#pragma unroll
  for (int j = 0; j < 8; ++j) {
    const unsigned short* kp = K + gbase + (size_t)j * 1024 + coff;
    u16x8 a = *reinterpret_cast<const u16x8*>(kp);
    u16x8 b = *reinterpret_cast<const u16x8*>(kp + 8);
    float kv[16];
#pragma unroll
    for (int c = 0; c < 8; ++c) { kv[c] = bf2f(a[c]); kv[8 + c] = bf2f(b[c]); }
#pragma unroll
    for (int r = 0; r < 4; ++r) {
      float acc = 0.f;
#pragma unroll
      for (int c = 0; c < 16; ++c) acc += q[r][c] * kv[c];
      s[r][j] += acc;
    }
  }

#pragma unroll
  for (int r = 0; r < 4; ++r)
#pragma unroll
    for (int j = 0; j < 8; ++j) {
      float v = s[r][j];
      v += __shfl_xor(v, 1, 64);
      v += __shfl_xor(v, 2, 64);
      s[r][j] = v;
    }

  float p[4][8];
#pragma unroll
  for (int r = 0; r < 4; ++r) {
    float mx = s[r][0];
#pragma unroll
    for (int j = 1; j < 8; ++j) mx = fmaxf(mx, s[r][j]);
    float sum = 0.f;
#pragma unroll
    for (int j = 0; j < 8; ++j) {
      float e = __expf(0.125f * (s[r][j] - mx));  // SCALE = 1/sqrt(64)
      p[r][j] = e;
      sum += e;
    }
    float inv = 1.f / sum;
#pragma unroll
    for (int j = 0; j < 8; ++j) p[r][j] *= inv;
  }

  float o[4][16];
#pragma unroll
  for (int r = 0; r < 4; ++r)
#pragma unroll
    for (int c = 0; c < 16; ++c) o[r][c] = 0.f;

#pragma unroll
  for (int j = 0; j < 8; ++j) {
    const unsigned short* vp = V + gbase + (size_t)j * 1024 + coff;
    u16x8 a = *reinterpret_cast<const u16x8*>(vp);
    u16x8 b = *reinterpret_cast<const u16x8*>(vp + 8);
    float vv[16];
#pragma unroll
    for (int c = 0; c < 8; ++c) { vv[c] = bf2f(a[c]); vv[8 + c] = bf2f(b[c]); }
#pragma unroll
    for (int r = 0; r < 4; ++r)
#pragma unroll
      for (int c = 0; c < 16; ++c) o[r][c] += p[r][j] * vv[c];
  }

#pragma unroll
  for (int r = 0; r < 4; ++r) {
    float* op = out + gbase + (size_t)(rh * 4 + r) * 1024 + coff;
    f32x4 v0 = {o[r][0], o[r][1], o[r][2], o[r][3]};
    f32x4 v1 = {o[r][4], o[r][5], o[r][6], o[r][7]};
    f32x4 v2 = {o[r][8], o[r][9], o[r][10], o[r][11]};
    f32x4 v3 = {o[r][12], o[r][13], o[r][14], o[r][15]};
    reinterpret_cast<f32x4*>(op)[0] = v0;
    reinterpret_cast<f32x4*>(op)[1] = v1;
    reinterpret_cast<f32x4*>(op)[2] = v2;
    reinterpret_cast<f32x4*>(op)[3] = v3;
  }
}

// ------------------------------------------------------------------- launch
extern "C" void kernel_launch(void* const* d_in, const int* in_sizes, int n_in,
                              void* d_out, int out_size, void* d_ws, size_t ws_size,
                              hipStream_t stream) {
  const float* Xq = (const float*)d_in[0];
  const float* Xk = (const float*)d_in[1];
  const float* Xv = (const float*)d_in[2];
  const float* Wq = (const float*)d_in[3];
  const float* bq = (const float*)d_in[4];
  const float* Wk = (const float*)d_in[5];
  const float* bk = (const float*)d_in[6];
  const float* Wv = (const float*)d_in[7];
  const float* bv = (const float*)d_in[8];

  unsigned short* ws = (unsigned short*)d_ws;
  unsigned short* Wb = ws;                              // 3 x 1M bf16 (6 MB), pre-swizzled
  unsigned short* QKV = ws + (size_t)3 * 1024 * 1024;   // 3 x 8M bf16 (48 MB)

  cvt_w_swz<<<1536, 256, 0, stream>>>(Wq, Wk, Wv, Wb);
  gemm_qkv2<<<dim3(64, 4, 3), 512, 0, stream>>>(Xq, Xk, Xv, Wb, bq, bk, bv, QKV);
  attn_kernel<<<512, 256, 0, stream>>>(QKV, (float*)d_out);
}